// Round 10
// baseline (23860.794 us; speedup 1.0000x reference)
//
#include <hip/hip_runtime.h>
#include <hip/hip_bf16.h>

// LSTM: B=64, S=512, H=768, L=2. Persistent scan per layer, 12 waves/WG.
//   waves 0-5 (x): input projection, 1 step ahead, LDS ring.
//   waves 6-11 (h): recurrent projection; half0 waves poll+stage h into LDS;
//                   half1 waves finalize gates/state and publish h.
// ROUND 10: weights pre-split ONCE into per-wave fragment layout (prep
// kernel) -> per-step weight access = 24 coalesced L2-hit 16B loads, zero
// VALU, allocator-proof (round 8/9: compiler refused register residency and
// re-split fp32 weights every step). h exchange: packed u32 MALL ring[2] +
// per-(group,step) counter + LDS staging (dedups 6x per-wave h reads).

#define HID 768
#define FH  3072
#define SEQ 512
#define BAT 64
#define GB  16           // batches per group
#define WPG 64           // workgroups per group
#define CPW 12           // h-columns per workgroup (3 tiles x 4 cols)
#define NWG 256
#define TPB 768          // 12 waves
#define LROW 772         // padded LDS row stride (u32) for hbuf
#define WBLK (12*64*8)   // u32 per wave weight block (6144)

typedef __attribute__((ext_vector_type(8))) __bf16 bf16x8;
typedef __attribute__((ext_vector_type(4))) float f32x4;
typedef unsigned int u32;
typedef unsigned long long u64;

__device__ __forceinline__ float sigm(float z) { return 1.f / (1.f + __expf(-z)); }
__device__ __forceinline__ float tanh_fast(float x) {
  float a = fabsf(x);
  float e = __expf(-2.f * a);
  float t = (1.f - e) / (1.f + e);
  return copysignf(t, x);
}
__device__ __forceinline__ unsigned short bfbits(__bf16 b) {
  union { __bf16 b; unsigned short s; } u; u.b = b; return u.s;
}
__device__ __forceinline__ __bf16 bits2bf(unsigned short s) {
  union { unsigned short s; __bf16 b; } u; u.s = s; return u.b;
}
__device__ __forceinline__ u32 packsplit(float v) {
  __bf16 h = (__bf16)v;
  __bf16 l = (__bf16)(v - (float)h);
  return ((u32)bfbits(h) << 16) | (u32)bfbits(l);
}
__device__ __forceinline__ void split8(const float* p, bf16x8& hi, bf16x8& lo) {
  const float4* q = (const float4*)p;
  float4 a = q[0], b = q[1];
  float v[8] = {a.x, a.y, a.z, a.w, b.x, b.y, b.z, b.w};
#pragma unroll
  for (int i = 0; i < 8; ++i) {
    __bf16 h = (__bf16)v[i];
    hi[i] = h;
    lo[i] = (__bf16)(v[i] - (float)h);
  }
}
__device__ __forceinline__ void unpack8(const u32 w[8], bf16x8& hi, bf16x8& lo) {
#pragma unroll
  for (int i = 0; i < 8; ++i) {
    hi[i] = bits2bf((unsigned short)(w[i] >> 16));
    lo[i] = bits2bf((unsigned short)(w[i] & 0xffffu));
  }
}
__device__ __forceinline__ bf16x8 q2b(uint4 q) {
  union { uint4 q; bf16x8 v; } u; u.q = q; return u.v;
}
__device__ __forceinline__ uint4 b2q(bf16x8 v) {
  union { bf16x8 v; uint4 q; } u; u.v = v; return u.q;
}

// ---- prep: split W into per-wave fragment layout ----
// t = ((((layer*2+proj)*64 + wid)*6 + lane6)*12 + kk)*64 + lane, unit = 32B.
__global__ void pack_w(const float* __restrict__ Wih,
                       const float* __restrict__ Whh,
                       u32* __restrict__ wpk) {
  const int NT = 2*2*64*6*12*64;     // 1,179,648
  int t = blockIdx.x * blockDim.x + threadIdx.x;
  if (t >= NT) return;
  int lane = t & 63; int r = t >> 6;
  int kk = r % 12;  r /= 12;
  int lane6 = r % 6; r /= 6;
  int wid = r % 64; r /= 64;
  int proj = r & 1; int layer = r >> 1;
  int tile = lane6 >> 1, half = lane6 & 1;
  int l15 = lane & 15, lhi = lane >> 4;
  int colA = wid*CPW + tile*4 + (l15 >> 2);
  int qA   = l15 & 3;
  int row  = qA*HID + colA;
  int k    = half*384 + kk*32 + lhi*8;
  const float* W = (proj == 0 ? Wih : Whh) + (size_t)layer*FH*HID;
  bf16x8 hi, lo;
  split8(W + (size_t)row*HID + k, hi, lo);
  u32* dst = wpk + (size_t)t * 8;
  *(uint4*)dst       = b2q(hi);
  *(uint4*)(dst + 4) = b2q(lo);
}

// K=384 projection: weights from pre-split wpk block, B from global.
template<int FMT>
__device__ __forceinline__ f32x4 projW(const float* xf, const u32* xp,
                                       size_t base, const u32* wb, int l) {
  f32x4 acc[4];
#pragma unroll
  for (int r = 0; r < 4; ++r) acc[r] = f32x4{0.f, 0.f, 0.f, 0.f};
#pragma unroll
  for (int kk = 0; kk < 12; ++kk) {
    const uint4* wp = (const uint4*)(wb + (size_t)(kk*64 + l)*8);
    bf16x8 Ah = q2b(wp[0]);
    bf16x8 Al = q2b(wp[1]);
    bf16x8 bhi, blo;
    if constexpr (FMT == 0) {
      split8(xf + base + kk*32, bhi, blo);
    } else {
      const uint4* p = (const uint4*)(xp + base + kk*32);
      uint4 A = p[0], B = p[1];
      u32 w[8] = {A.x, A.y, A.z, A.w, B.x, B.y, B.z, B.w};
      unpack8(w, bhi, blo);
    }
    acc[(3*kk+0)&3] = __builtin_amdgcn_mfma_f32_16x16x32_bf16(Ah, bhi, acc[(3*kk+0)&3], 0, 0, 0);
    acc[(3*kk+1)&3] = __builtin_amdgcn_mfma_f32_16x16x32_bf16(Al, bhi, acc[(3*kk+1)&3], 0, 0, 0);
    acc[(3*kk+2)&3] = __builtin_amdgcn_mfma_f32_16x16x32_bf16(Ah, blo, acc[(3*kk+2)&3], 0, 0, 0);
  }
  return acc[0] + acc[1] + acc[2] + acc[3];
}

template<int XFMT, int WRITE_OUT>
__global__ void __launch_bounds__(TPB)
lstm_scan(const float* __restrict__ xf,   // XFMT==0: raw x [64][512][768] fp32
          const u32* __restrict__ xp,     // XFMT==1: packed pairs [512][64][768]
          const float* __restrict__ mask, // [64][512]
          const u32* __restrict__ wpk,    // this layer's pre-split weights
          const float* __restrict__ bih,  // this layer
          const float* __restrict__ bhh,
          u32* __restrict__ hstream,      // !WRITE_OUT: full h stream (L1 input)
          u32* __restrict__ ring,         // [2][64][768] packed u32, MALL ring
          float* __restrict__ out_f,      // WRITE_OUT: [64][512][768]
          float* __restrict__ hn,         // [64][768] this layer
          float* __restrict__ cn,
          int* __restrict__ cnt)          // [4][512] counters, zeroed
{
  __shared__ u32 hbuf[16 * LROW];         // staged h slice (49.4 KB)
  __shared__ f32x4 xacc_l[4][3][64];      // x-proj ring (12 KB)
  __shared__ f32x4 xpart_l[3][64];        // x K-half partial (3 KB)
  __shared__ f32x4 hpart_l[2][3][64];     // h K-half partial (6 KB)
  __shared__ int lctr[SEQ];               // finalize election (2 KB)

  const int wg  = blockIdx.x;
  const int grp = wg >> 6;
  const int wid = wg & 63;
  const int tid = threadIdx.x;
  const int wv  = tid >> 6;        // 0..11
  const int l   = tid & 63;
  const int l15 = l & 15;
  const int lhi = l >> 4;

  const bool isx  = (wv < 6);
  const int lane6 = isx ? wv : (wv - 6);
  const int tile  = lane6 >> 1;    // 0..2
  const int half  = lane6 & 1;
  const int kofs  = half * 384;

  const u32* wbase = wpk + ((size_t)((isx ? 0 : 1)*64 + wid)*6 + lane6) * WBLK;

  const int batch = grp*GB + l15;
  const int colO  = wid*CPW + tile*4 + lhi;
  float bias4[4] = {0.f, 0.f, 0.f, 0.f};
  if (!isx && half == 1) {
#pragma unroll
    for (int j = 0; j < 4; ++j) bias4[j] = bih[j*HID + colO] + bhh[j*HID + colO];
  }
  const float* mrow = mask + batch*SEQ;
  int* cntg = cnt + grp*SEQ;
  const int kb = kofs + lhi*8;

  for (int i = tid; i < SEQ; i += TPB) lctr[i] = 0;

  float cstate = 0.f;

  // ---- prologue: xacc(0) ----
  {
    f32x4 px{0.f, 0.f, 0.f, 0.f};
    if (isx) {
      size_t base = (XFMT == 0) ? ((size_t)batch*SEQ)*HID + kb
                                : ((size_t)batch)*HID + kb;
      px = projW<XFMT>(xf, xp, base, wbase, l);
      if (half == 0) xpart_l[tile][l] = px;
    }
    __syncthreads();
    if (isx && half == 1) xacc_l[0][tile][l] = px + xpart_l[tile][l];
    __syncthreads();
  }

#pragma unroll 1
  for (int s = 0; s < SEQ; ++s) {
    // ---- phase0: x-waves compute s+1; half0 h-waves poll + stage h(s-1) ----
    f32x4 xa{0.f, 0.f, 0.f, 0.f};
    if (isx) {
      if (s + 1 < SEQ) {
        size_t base = (XFMT == 0) ? ((size_t)batch*SEQ + (s+1))*HID + kb
                                  : ((size_t)(s+1)*BAT + batch)*HID + kb;
        xa = projW<XFMT>(xf, xp, base, wbase, l);
        if (half == 0) xpart_l[tile][l] = xa;
      }
    } else if (half == 0 && s > 0) {
      const int* cp = cntg + (s - 1);
      while (__hip_atomic_load(cp, __ATOMIC_RELAXED, __HIP_MEMORY_SCOPE_AGENT) < 64)
        __builtin_amdgcn_s_sleep(1);
      // stage group's h(s-1) slice (16x768 u32) into LDS, row-padded
      const u32* rsrc = ring + (size_t)(((s-1) & 1)*BAT + grp*GB)*HID;
      const int hlid = tile*64 + l;          // 0..191
#pragma unroll
      for (int i = 0; i < 16; ++i) {
        const u64* sp = (const u64*)(rsrc + (size_t)i*HID + hlid*4);
        u64 a = __hip_atomic_load(sp,     __ATOMIC_RELAXED, __HIP_MEMORY_SCOPE_AGENT);
        u64 b = __hip_atomic_load(sp + 1, __ATOMIC_RELAXED, __HIP_MEMORY_SCOPE_AGENT);
        *(uint4*)&hbuf[i*LROW + hlid*4] =
            make_uint4((u32)a, (u32)(a >> 32), (u32)b, (u32)(b >> 32));
      }
    }
    __syncthreads();   // b1: staging + xpart visible

    // ---- phase1: h-waves MFMA from LDS; x half1 folds xacc(s+1) ----
    f32x4 ha{0.f, 0.f, 0.f, 0.f};
    if (!isx && s > 0) {
      f32x4 acc[4];
#pragma unroll
      for (int r = 0; r < 4; ++r) acc[r] = f32x4{0.f, 0.f, 0.f, 0.f};
#pragma unroll
      for (int kk = 0; kk < 12; ++kk) {
        const uint4* wp = (const uint4*)(wbase + (size_t)(kk*64 + l)*8);
        bf16x8 Ah = q2b(wp[0]);
        bf16x8 Al = q2b(wp[1]);
        int hb = l15*LROW + kofs + kk*32 + lhi*8;
        uint4 qa = *(const uint4*)&hbuf[hb];
        uint4 qb = *(const uint4*)&hbuf[hb + 4];
        u32 w[8] = {qa.x, qa.y, qa.z, qa.w, qb.x, qb.y, qb.z, qb.w};
        bf16x8 bhi, blo;
        unpack8(w, bhi, blo);
        acc[(3*kk+0)&3] = __builtin_amdgcn_mfma_f32_16x16x32_bf16(Ah, bhi, acc[(3*kk+0)&3], 0, 0, 0);
        acc[(3*kk+1)&3] = __builtin_amdgcn_mfma_f32_16x16x32_bf16(Al, bhi, acc[(3*kk+1)&3], 0, 0, 0);
        acc[(3*kk+2)&3] = __builtin_amdgcn_mfma_f32_16x16x32_bf16(Ah, blo, acc[(3*kk+2)&3], 0, 0, 0);
      }
      ha = acc[0] + acc[1] + acc[2] + acc[3];
      if (half == 0) hpart_l[s & 1][tile][l] = ha;
    }
    if (isx && half == 1 && s + 1 < SEQ)
      xacc_l[(s+1) & 3][tile][l] = xa + xpart_l[tile][l];
    __syncthreads();   // b2: hpart + xacc ready

    // ---- phase2: finalize (h half1 waves); others run ahead to phase0(s+1) ----
    if (!isx && half == 1) {
      f32x4 z = xacc_l[s & 3][tile][l];
      if (s > 0) z = z + ha + hpart_l[s & 1][tile][l];
      float zi = z[0] + bias4[0], zf = z[1] + bias4[1];
      float zg = z[2] + bias4[2], zo = z[3] + bias4[3];
      float iv = sigm(zi), fv = sigm(zf), gv = tanh_fast(zg), ov = sigm(zo);
      float c  = fv*cstate + iv*gv;
      float hv = ov * tanh_fast(c);
      float m  = mrow[s];
      hv *= m; c *= m; cstate = c;

      u32 hw = packsplit(hv);
      __hip_atomic_store(ring + ((size_t)(s & 1)*BAT + batch)*HID + colO, hw,
                         __ATOMIC_RELAXED, __HIP_MEMORY_SCOPE_AGENT);
      if constexpr (!WRITE_OUT) {
        __builtin_nontemporal_store(hw, hstream + ((size_t)s*BAT + batch)*HID + colO);
      } else {
        __builtin_nontemporal_store(hv, out_f + ((size_t)batch*SEQ + s)*HID + colO);
      }
      if (s == SEQ - 1) {
        hn[batch*HID + colO] = hv;
        cn[batch*HID + colO] = c;
      }
      asm volatile("s_waitcnt vmcnt(0)" ::: "memory");
      if (l == 0) {
        int old = atomicAdd(&lctr[s], 1);
        if (old == 2)
          __hip_atomic_fetch_add(cntg + s, 1, __ATOMIC_RELAXED, __HIP_MEMORY_SCOPE_AGENT);
      }
    }
  }
}

extern "C" void kernel_launch(void* const* d_in, const int* in_sizes, int n_in,
                              void* d_out, int out_size, void* d_ws, size_t ws_size,
                              hipStream_t stream) {
  const float* x    = (const float*)d_in[0];
  const float* mask = (const float*)d_in[1];
  const float* Wih  = (const float*)d_in[2];
  const float* Whh  = (const float*)d_in[3];
  const float* bih  = (const float*)d_in[4];
  const float* bhh  = (const float*)d_in[5];
  float* out = (float*)d_out;

  char* ws = (char*)d_ws;
  const size_t WPK_B = (size_t)2*2*64*6*12*64*8 * 4;          // 37,748,736
  const size_t H0_B  = (size_t)SEQ*BAT*HID*4;                 // 100,663,296
  const size_t RING_B = (size_t)2*BAT*HID*4;                  // 393,216
  u32* wpk  = (u32*)ws;
  u32* h0pk = (u32*)(ws + WPK_B);
  u32* ring = (u32*)(ws + WPK_B + H0_B);
  int* cnt  = (int*)(ws + WPK_B + H0_B + RING_B);             // [2][4][512]

  (void)hipMemsetAsync(cnt, 0, 2*4*SEQ*sizeof(int), stream);
  pack_w<<<4608, 256, 0, stream>>>(Wih, Whh, wpk);

  float* hn = out + 25165824;             // [2][64][768]
  float* cn = out + 25165824 + 98304;

  const size_t WLAYER = (size_t)2*64*6*WBLK;  // u32 per layer = 4,718,592

  // ---- layer 0: raw fp32 x, writes h0pk stream ----
  lstm_scan<0, 0><<<dim3(NWG), dim3(TPB), 0, stream>>>(
      x, nullptr, mask, wpk, bih, bhh,
      h0pk, ring, nullptr, hn, cn, cnt);

  // ---- layer 1: h0pk input, writes out ----
  lstm_scan<1, 1><<<dim3(NWG), dim3(TPB), 0, stream>>>(
      nullptr, h0pk, mask, wpk + WLAYER, bih + FH, bhh + FH,
      nullptr, ring, out, hn + 49152, cn + 49152, cnt + 4*SEQ);
}

// Round 11
// 11576.995 us; speedup vs baseline: 2.0611x; 2.0611x over previous
//
#include <hip/hip_runtime.h>
#include <hip/hip_bf16.h>

// LSTM: B=64, S=512, H=768, L=2. Persistent scan per layer, 12 waves/WG
// (round-8 skeleton, best measured).
//   waves 0-5 (x): input projection, 1 step ahead, LDS ring.
//   waves 6-11 (h): recurrent projection; wave 6 polls; half1 waves finalize.
// ROUND 11 (two compile-level changes, one theory: compiler VGPR budget):
//   1. LDS padded to 82944B (xacc ring declared [24], indexed &3) -> only
//      1 block/CU fits -> compiler budgets 3 waves/SIMD = 170 VGPRs/wave ->
//      the 96-VGPR weight fragments stay register-resident (rounds 8-10:
//      VGPR_Count 84/60 = budget for a phantom 2nd block; weights re-loaded
//      + re-split EVERY step = ~75 MB/step LLC traffic = the 13 us/step).
//   2. amdgpu_waves_per_eu(3,3) correctly placed before __global__.
// h exchange: MALL-bypass relaxed-agent stores + vmcnt ack + flag; consumers
// plain cached loads on write-once streams (round-5-proven protocol).

#define HID 768
#define FH  3072
#define SEQ 512
#define BAT 64
#define GB  16           // batches per group
#define WPG 64           // workgroups per group
#define CPW 12           // h-columns per workgroup (3 tiles x 4 cols)
#define NWG 256
#define TPB 768          // 12 waves

typedef __attribute__((ext_vector_type(8))) __bf16 bf16x8;
typedef __attribute__((ext_vector_type(4))) float f32x4;
typedef unsigned int u32;

__device__ __forceinline__ float sigm(float z) { return 1.f / (1.f + __expf(-z)); }
__device__ __forceinline__ float tanh_fast(float x) {
  float a = fabsf(x);
  float e = __expf(-2.f * a);
  float t = (1.f - e) / (1.f + e);
  return copysignf(t, x);
}
__device__ __forceinline__ unsigned short bfbits(__bf16 b) {
  union { __bf16 b; unsigned short s; } u; u.b = b; return u.s;
}
__device__ __forceinline__ __bf16 bits2bf(unsigned short s) {
  union { unsigned short s; __bf16 b; } u; u.s = s; return u.b;
}
__device__ __forceinline__ u32 packsplit(float v) {
  __bf16 h = (__bf16)v;
  __bf16 l = (__bf16)(v - (float)h);
  return ((u32)bfbits(h) << 16) | (u32)bfbits(l);
}
__device__ __forceinline__ void split8(const float* p, bf16x8& hi, bf16x8& lo) {
  const float4* q = (const float4*)p;
  float4 a = q[0], b = q[1];
  float v[8] = {a.x, a.y, a.z, a.w, b.x, b.y, b.z, b.w};
#pragma unroll
  for (int i = 0; i < 8; ++i) {
    __bf16 h = (__bf16)v[i];
    hi[i] = h;
    lo[i] = (__bf16)(v[i] - (float)h);
  }
}
__device__ __forceinline__ void unpack8(const u32 w[8], bf16x8& hi, bf16x8& lo) {
#pragma unroll
  for (int i = 0; i < 8; ++i) {
    hi[i] = bits2bf((unsigned short)(w[i] >> 16));
    lo[i] = bits2bf((unsigned short)(w[i] & 0xffffu));
  }
}

// K=384 projection slice: 12 chunks x 3 MFMAs, returns summed D fragment.
// FMT 0: fp32 source (split on the fly); FMT 1: packed hi|lo u32 pairs.
template<int FMT>
__device__ __forceinline__ f32x4 proj384(const float* xf, const u32* xp,
                                         size_t base,
                                         const bf16x8* ah, const bf16x8* al) {
  f32x4 acc[4];
#pragma unroll
  for (int r = 0; r < 4; ++r) acc[r] = f32x4{0.f, 0.f, 0.f, 0.f};
#pragma unroll
  for (int kk = 0; kk < 12; ++kk) {
    bf16x8 bhi, blo;
    if constexpr (FMT == 0) {
      split8(xf + base + kk*32, bhi, blo);
    } else {
      const uint4* p = (const uint4*)(xp + base + kk*32);
      uint4 A = p[0], B = p[1];
      u32 w[8] = {A.x, A.y, A.z, A.w, B.x, B.y, B.z, B.w};
      unpack8(w, bhi, blo);
    }
    acc[(3*kk+0)&3] = __builtin_amdgcn_mfma_f32_16x16x32_bf16(ah[kk], bhi, acc[(3*kk+0)&3], 0, 0, 0);
    acc[(3*kk+1)&3] = __builtin_amdgcn_mfma_f32_16x16x32_bf16(al[kk], bhi, acc[(3*kk+1)&3], 0, 0, 0);
    acc[(3*kk+2)&3] = __builtin_amdgcn_mfma_f32_16x16x32_bf16(ah[kk], blo, acc[(3*kk+2)&3], 0, 0, 0);
  }
  return acc[0] + acc[1] + acc[2] + acc[3];
}

template<int XFMT, int WRITE_OUT>
__attribute__((amdgpu_waves_per_eu(3, 3)))
__global__ void __launch_bounds__(TPB)
lstm_scan(const float* __restrict__ xf,   // XFMT==0: raw x [64][512][768] fp32
          const u32* __restrict__ xp,     // XFMT==1: packed pairs [512][64][768]
          const float* __restrict__ mask, // [64][512]
          const float* __restrict__ Wih,  // [3072][768] this layer
          const float* __restrict__ Whh,
          const float* __restrict__ bih,
          const float* __restrict__ bhh,
          u32* __restrict__ hstream,      // h stream [512][64][768] packed pairs
          float* __restrict__ out_f,      // WRITE_OUT: [64][512][768]
          float* __restrict__ hn,         // [64][768] this layer
          float* __restrict__ cn,
          int* __restrict__ flags)        // [NWG] this layer, zeroed
{
  // xacc ring uses slots 0..3 only; declared 24-deep to push static LDS past
  // 80 KB so the compiler can only fit 1 block/CU -> 170-VGPR/wave budget.
  __shared__ f32x4 xacc_l[24][3][64];     // 73728 B
  __shared__ f32x4 xpart_l[3][64];        // 3072 B
  __shared__ f32x4 hpart_l[2][3][64];     // 6144 B   (total 82944 B)

  const int wg  = blockIdx.x;
  const int grp = wg >> 6;
  const int wid = wg & 63;
  const int tid = threadIdx.x;
  const int wv  = tid >> 6;        // 0..11
  const int l   = tid & 63;
  const int l15 = l & 15;
  const int lhi = l >> 4;

  const bool isx  = (wv < 6);
  const int lane6 = isx ? wv : (wv - 6);
  const int tile  = lane6 >> 1;    // 0..2
  const int half  = lane6 & 1;     // K-half within the 768-K GEMM
  const int kofs  = half * 384;

  // ---- weights (split-bf16) -> registers: 12 chunks = 24 frags = 96 VGPRs.
  // A-fragment: M-row m = l15 = 4*c_loc + gate; k = kofs + kk*32 + lhi*8 + i
  const int colA = wid*CPW + tile*4 + (l15 >> 2);
  const int qA   = l15 & 3;
  const float* wrow = (isx ? Wih : Whh) + (size_t)(qA*HID + colA)*HID + kofs + lhi*8;
  bf16x8 ah[12], al[12];
#pragma unroll
  for (int kk = 0; kk < 12; ++kk) split8(wrow + kk*32, ah[kk], al[kk]);

  // ---- per-lane output ownership (D: col=l15 -> batch, elem j -> gate j of colO)
  const int batch = grp*GB + l15;
  const int colO  = wid*CPW + tile*4 + lhi;
  float bias4[4] = {0.f, 0.f, 0.f, 0.f};
  if (!isx && half == 1) {
#pragma unroll
    for (int j = 0; j < 4; ++j) bias4[j] = bih[j*HID + colO] + bhh[j*HID + colO];
  }
  const float* mrow = mask + batch*SEQ;
  int* gflags = flags + grp*WPG;

  const int kb = kofs + lhi*8;     // per-lane K element offset

  float cstate = 0.f;

  // ---- prologue: produce xacc(0) into ring slot 0 ----
  {
    f32x4 px{0.f, 0.f, 0.f, 0.f};
    if (isx) {
      size_t base = (XFMT == 0) ? ((size_t)batch*SEQ)*HID + kb
                                : ((size_t)batch)*HID + kb;
      px = proj384<XFMT>(xf, xp, base, ah, al);
      if (half == 0) xpart_l[tile][l] = px;
    }
    __syncthreads();
    if (isx && half == 1) xacc_l[0][tile][l] = px + xpart_l[tile][l];
    __syncthreads();
  }

#pragma unroll 1
  for (int s = 0; s < SEQ; ++s) {
    // ---- phase0: x-waves compute s+1; poller waits flag(s) ----
    f32x4 xa{0.f, 0.f, 0.f, 0.f};
    if (isx && s + 1 < SEQ) {
      size_t base = (XFMT == 0) ? ((size_t)batch*SEQ + (s+1))*HID + kb
                                : ((size_t)(s+1)*BAT + batch)*HID + kb;
      xa = proj384<XFMT>(xf, xp, base, ah, al);
      if (half == 0) xpart_l[tile][l] = xa;
    }
    if (!isx && lane6 == 0 && s > 0) {     // wave 6 polls for the whole WG
      while (true) {
        int v = __hip_atomic_load(gflags + l, __ATOMIC_RELAXED, __HIP_MEMORY_SCOPE_AGENT);
        if (__all(v >= s)) break;
        __builtin_amdgcn_s_sleep(1);
      }
    }
    __syncthreads();   // b1: flag released; xpart(s+1) visible

    // ---- phase1: h-waves load h(s-1) + MFMA; x half1 folds xacc(s+1) ----
    f32x4 ha{0.f, 0.f, 0.f, 0.f};
    if (!isx && s > 0) {
      size_t base = ((size_t)(s-1)*BAT + batch)*HID + kb;
      ha = proj384<1>(nullptr, hstream, base, ah, al);
      if (half == 0) hpart_l[s & 1][tile][l] = ha;
    }
    if (isx && half == 1 && s + 1 < SEQ)
      xacc_l[(s+1) & 3][tile][l] = xa + xpart_l[tile][l];
    __syncthreads();   // b2: hpart + xacc ready

    // ---- phase2: finalize (h half1 waves own the output) ----
    if (!isx && half == 1) {
      f32x4 z = xacc_l[s & 3][tile][l];
      if (s > 0) z = z + ha + hpart_l[s & 1][tile][l];
      float zi = z[0] + bias4[0], zf = z[1] + bias4[1];
      float zg = z[2] + bias4[2], zo = z[3] + bias4[3];
      float iv = sigm(zi), fv = sigm(zf), gv = tanh_fast(zg), ov = sigm(zo);
      float c  = fv*cstate + iv*gv;
      float hv = ov * tanh_fast(c);
      float m  = mrow[s];
      hv *= m; c *= m; cstate = c;

      u32 hw = packsplit(hv);
      __hip_atomic_store(hstream + ((size_t)s*BAT + batch)*HID + colO, hw,
                         __ATOMIC_RELAXED, __HIP_MEMORY_SCOPE_AGENT);
      if constexpr (WRITE_OUT) {
        __builtin_nontemporal_store(hv, out_f + ((size_t)batch*SEQ + s)*HID + colO);
      }
      if (s == SEQ - 1) {
        hn[batch*HID + colO] = hv;
        cn[batch*HID + colO] = c;
      }
      asm volatile("s_waitcnt vmcnt(0)" ::: "memory");  // h at MALL before flag
    }
    __syncthreads();   // b3: all finalizers drained
    if (tid == 0)
      __hip_atomic_store(gflags + wid, s + 1,
                         __ATOMIC_RELAXED, __HIP_MEMORY_SCOPE_AGENT);
  }
}

extern "C" void kernel_launch(void* const* d_in, const int* in_sizes, int n_in,
                              void* d_out, int out_size, void* d_ws, size_t ws_size,
                              hipStream_t stream) {
  const float* x    = (const float*)d_in[0];
  const float* mask = (const float*)d_in[1];
  const float* Wih  = (const float*)d_in[2];
  const float* Whh  = (const float*)d_in[3];
  const float* bih  = (const float*)d_in[4];
  const float* bhh  = (const float*)d_in[5];
  float* out = (float*)d_out;

  char* ws = (char*)d_ws;
  const size_t STREAM_B = (size_t)SEQ * BAT * HID * sizeof(u32);  // 100663296
  u32* opk   = (u32*)(ws);                // L0 h-stream = L1 input
  u32* hpk   = (u32*)(ws + STREAM_B);     // L1 h-stream
  int* flags = (int*)(ws + 2*STREAM_B);   // 2*NWG*4

  (void)hipMemsetAsync(flags, 0, 2*NWG*sizeof(int), stream);

  float* hn = out + 25165824;             // [2][64][768]
  float* cn = out + 25165824 + 98304;

  // ---- layer 0: raw fp32 x input, h-stream -> opk ----
  lstm_scan<0, 0><<<dim3(NWG), dim3(TPB), 0, stream>>>(
      x, nullptr, mask, Wih, Whh, bih, bhh,
      opk, nullptr, hn, cn, flags);

  // ---- layer 1: packed opk input, h-stream -> hpk, writes out ----
  lstm_scan<1, 1><<<dim3(NWG), dim3(TPB), 0, stream>>>(
      nullptr, opk, mask,
      Wih + (size_t)FH*HID, Whh + (size_t)FH*HID, bih + FH, bhh + FH,
      hpk, out, hn + 49152, cn + 49152, flags + NWG);
}